// Round 12
// baseline (78.189 us; speedup 1.0000x reference)
//
#include <hip/hip_runtime.h>
#include <hip/hip_bf16.h>

typedef unsigned short u16;
typedef unsigned int u32;
typedef float f32x4 __attribute__((ext_vector_type(4)));
typedef short s16x8 __attribute__((ext_vector_type(8)));

#define MFMA_BF16(a, b, c) __builtin_amdgcn_mfma_f32_16x16x32_bf16((a), (b), (c), 0, 0, 0)

// Problem constants: B=8, T=2048, D=1024, HS=64; scale = 1/sqrt(2048) (per reference!)

__device__ __forceinline__ u16 f2bf(float f) {
  union { float f; u32 u; } v; v.f = f;
  u32 u = v.u;
  return (u16)((u + 0x7FFFu + ((u >> 16) & 1u)) >> 16);  // RNE f32->bf16
}
__device__ __forceinline__ u16 f2bf_t(float f) {  // truncating f32->bf16 (P tile only)
  union { float f; u32 u; } v; v.f = f;
  return (u16)(v.u >> 16);
}
// native pack: compiler emits v_cvt_pk_bf16_f32 (4 instrs for 8 elems)
__device__ __forceinline__ s16x8 pack_bf8(float4 a, float4 b) {
  union { __hip_bfloat162 h2[4]; s16x8 s; } u;
  u.h2[0] = __float22bfloat162_rn(make_float2(a.x, a.y));
  u.h2[1] = __float22bfloat162_rn(make_float2(a.z, a.w));
  u.h2[2] = __float22bfloat162_rn(make_float2(b.x, b.y));
  u.h2[3] = __float22bfloat162_rn(make_float2(b.z, b.w));
  return u.s;
}

// ---- Kernel 1: W [1024][64] f32 x3 -> Wt2 bf16 in K-MAJOR layout:
// element (row, d) -> Wt2[((d>>3)*192 + row)*8 + (d&7)], rows: q 0-63, k 64-127, v 128-191.
__global__ __launch_bounds__(256) void wt_convert(const float* __restrict__ Wq,
                                                  const float* __restrict__ Wk,
                                                  const float* __restrict__ Wv,
                                                  u16* __restrict__ Wt2) {
  __shared__ u16 Ls[64][70];
  const int bid = blockIdx.x;
  const int m = bid >> 4, d0 = (bid & 15) * 64;
  const float* W = (m == 0) ? Wq : (m == 1) ? Wk : Wv;
  const int t = threadIdx.x;
  {
    const int dr = t >> 2, hc = (t & 3) * 16;
    const float4* src = (const float4*)(W + (size_t)(d0 + dr) * 64 + hc);
    float4 f0 = src[0], f1 = src[1], f2 = src[2], f3 = src[3];
    float fl[16] = {f0.x, f0.y, f0.z, f0.w, f1.x, f1.y, f1.z, f1.w,
                    f2.x, f2.y, f2.z, f2.w, f3.x, f3.y, f3.z, f3.w};
#pragma unroll
    for (int j = 0; j < 8; ++j) {
      u32 pk = (u32)f2bf(fl[2 * j]) | ((u32)f2bf(fl[2 * j + 1]) << 16);
      *(u32*)&Ls[dr][hc + 2 * j] = pk;
    }
  }
  __syncthreads();
  {
    const int h = t >> 2, dcs = (t & 3) * 16;
    const int row = m * 64 + h;
    u32 po[8];
#pragma unroll
    for (int j = 0; j < 8; ++j)
      po[j] = (u32)Ls[dcs + 2 * j][h] | ((u32)Ls[dcs + 2 * j + 1][h] << 16);
    const int kg0 = (d0 + dcs) >> 3;
    *(uint4*)&Wt2[((size_t)kg0 * 192 + row) * 8] = make_uint4(po[0], po[1], po[2], po[3]);
    *(uint4*)&Wt2[((size_t)(kg0 + 1) * 192 + row) * 8] = make_uint4(po[4], po[5], po[6], po[7]);
  }
}

// ---- Kernel 2: QKV projection, ATTN-SHAPED: no LDS, no barriers, per-wave
// independent full-K loop with 1-step register prefetch rotation (the pattern
// attn_fwd proves works at ~300-500 TF effective on this chip/problem).
// C[16384,192] = X[16384,1024] @ W[1024,192], bf16 MFMA.
// grid 512 x 512 thr (8 waves) = 16 waves/CU. Block = 32 rows x 192 cols.
// Wave (msub=w&1, ntg=w>>1): 16 rows x 3 n-tiles, acc[3] (12 VGPR).
// Per k-step (BK=32): 2 float4 x-loads + 3 s16x8 W-loads (k-major Wt2: 16 lanes
// contiguous 256B per (hi,kk,j) -> 4-segment coalesced, L2-resident) + 3 MFMA.
// Native v_cvt_pk pack between load and MFMA (was ~36 VALU ops, now ~4).
__global__ __launch_bounds__(512) void qkv_gemm(const float* __restrict__ x,
                                                const u16* __restrict__ Wt2,
                                                u16* __restrict__ qo,
                                                u16* __restrict__ ko,
                                                u16* __restrict__ vTo) {
  const int tid = threadIdx.x, lane = tid & 63, w = tid >> 6;
  const int lc = lane & 15, hi = lane >> 4;
  const int m0 = blockIdx.x * 32;
  const int msub = w & 1, ntg = w >> 1;  // 2 m-subtiles x 4 n-groups (3 n-tiles each)

  f32x4 acc[3];
#pragma unroll
  for (int i = 0; i < 3; ++i) acc[i] = (f32x4){0.f, 0.f, 0.f, 0.f};

  // A: lane -> row = msub*16+lc, k-offset hi*8 within each 32-wide k-step.
  const float4* xp = (const float4*)(x + (size_t)(m0 + msub * 16 + lc) * 1024 + hi * 8);
  // B: lane -> col row = ntg*48 + j*16 + lc, same k-offset; k-major Wt2.
  const u16* wp = Wt2 + ((size_t)hi * 192 + ntg * 48 + lc) * 8;

  // prologue: step-0 operands
  float4 xa = xp[0], xb = xp[1];
  s16x8 b0 = *(const s16x8*)(wp);
  s16x8 b1 = *(const s16x8*)(wp + 128);
  s16x8 b2 = *(const s16x8*)(wp + 256);

  for (int kk = 0; kk < 32; ++kk) {
    float4 na, nb;
    s16x8 n0, n1, n2;
    if (kk < 31) {  // prefetch next step (attn's rotation pattern)
      na = xp[kk * 8 + 8];
      nb = xp[kk * 8 + 9];
      const u16* wn = wp + (size_t)(kk + 1) * 6144;
      n0 = *(const s16x8*)(wn);
      n1 = *(const s16x8*)(wn + 128);
      n2 = *(const s16x8*)(wn + 256);
    }
    s16x8 a = pack_bf8(xa, xb);
    acc[0] = MFMA_BF16(a, b0, acc[0]);
    acc[1] = MFMA_BF16(a, b1, acc[1]);
    acc[2] = MFMA_BF16(a, b2, acc[2]);
    if (kk < 31) { xa = na; xb = nb; b0 = n0; b1 = n1; b2 = n2; }
  }

  // epilogue: C layout col=lane&15, row=(lane>>4)*4+r
#pragma unroll
  for (int j = 0; j < 3; ++j) {
    const int nt = ntg * 3 + j;
#pragma unroll
    for (int r = 0; r < 4; ++r) {
      const int gr = m0 + msub * 16 + hi * 4 + r;
      const u16 val = f2bf(acc[j][r]);
      const int n = nt * 16 + lc;
      if (nt < 4) {
        qo[gr * 64 + n] = val;
      } else if (nt < 8) {
        ko[gr * 64 + (n - 64)] = val;
      } else {
        int b = gr >> 11, t2 = gr & 2047;
        vTo[((b << 6) + (n - 128)) * 2048 + t2] = val;
      }
    }
  }
}

// ---- Kernel 3: causal flash attention, no-max softmax. 256 threads = 4 waves.
// (unchanged from round 5: ~10-15us)
__global__ __launch_bounds__(256, 2) void attn_fwd(const u16* __restrict__ qb,
                                                   const u16* __restrict__ kb,
                                                   const u16* __restrict__ vT,
                                                   float* __restrict__ out) {
  __shared__ float PoS[4][32][66];  // per-wave merge buffer; P tile [32][40]u16 unioned in
  __shared__ float Pl[4][32];       // per-wave denominator partials
  const int tid = threadIdx.x, lane = tid & 63, w = tid >> 6;
  const int lc = lane & 15, hi = lane >> 4;
  const int bid = blockIdx.x;
  const int b = bid & 7, v = 63 - (bid >> 3);  // batch, q-tile id (heavy-first)
  const int q0 = v * 32;                       // q-tile base row within batch
  const int brow = b * 2048;
  u16* Pw = (u16*)&PoS[w][0][0];  // [32][40] u16 view, per-wave

  s16x8 aq[2][2];
#pragma unroll
  for (int sub = 0; sub < 2; ++sub) {
    const u16* qrow = qb + (size_t)(brow + q0 + sub * 16 + lc) * 64;
    aq[sub][0] = *(const s16x8*)(qrow + hi * 8);
    aq[sub][1] = *(const s16x8*)(qrow + 32 + hi * 8);
  }

  f32x4 o[2][4];
  float lrow[2][4];
#pragma unroll
  for (int sub = 0; sub < 2; ++sub)
#pragma unroll
    for (int i = 0; i < 4; ++i) {
      o[sub][i] = (f32x4){0.f, 0.f, 0.f, 0.f};
      lrow[sub][i] = 0.f;
    }

  const float SL = 0.031879357f;  // (1/sqrt(2048)) * log2(e)
  const int nk = v + 1;           // causal kv-tiles of 32 for this q-tile
  const int c = (nk + 3) >> 2;    // chunk per split-wave (4-way)
  const int s = w;
  const int it0 = s * c;
  const int it1 = min(it0 + c, nk);

  const u16* kbase = kb + (size_t)brow * 64;

  for (int it = it0; it < it1; ++it) {
    const int kvb = it * 32;
    const u16* krow0 = kbase + (size_t)(kvb + lc) * 64;
    const u16* krow1 = kbase + (size_t)(kvb + 16 + lc) * 64;
    s16x8 k00 = *(const s16x8*)(krow0 + hi * 8);
    s16x8 k01 = *(const s16x8*)(krow0 + 32 + hi * 8);
    s16x8 k10 = *(const s16x8*)(krow1 + hi * 8);
    s16x8 k11 = *(const s16x8*)(krow1 + 32 + hi * 8);
    s16x8 bv[4];
#pragma unroll
    for (int nt = 0; nt < 4; ++nt)
      bv[nt] = *(const s16x8*)&vT[(size_t)(b * 64 + nt * 16 + lc) * 2048 + kvb + hi * 8];

    f32x4 sc[2][2];
#pragma unroll
    for (int sub = 0; sub < 2; ++sub) {
      sc[sub][0] = (f32x4){0.f, 0.f, 0.f, 0.f};
      sc[sub][1] = (f32x4){0.f, 0.f, 0.f, 0.f};
      sc[sub][0] = MFMA_BF16(aq[sub][0], k00, sc[sub][0]);
      sc[sub][0] = MFMA_BF16(aq[sub][1], k01, sc[sub][0]);
      sc[sub][1] = MFMA_BF16(aq[sub][0], k10, sc[sub][1]);
      sc[sub][1] = MFMA_BF16(aq[sub][1], k11, sc[sub][1]);
    }

    if (kvb + 31 <= q0) {  // tile fully below diagonal: no masks
#pragma unroll
      for (int sub = 0; sub < 2; ++sub)
#pragma unroll
        for (int r = 0; r < 4; ++r) {
          float p0 = exp2f(sc[sub][0][r] * SL);
          float p1 = exp2f(sc[sub][1][r] * SL);
          lrow[sub][r] += p0 + p1;
          Pw[(sub * 16 + hi * 4 + r) * 40 + lc] = f2bf_t(p0);
          Pw[(sub * 16 + hi * 4 + r) * 40 + 16 + lc] = f2bf_t(p1);
        }
    } else {  // diagonal tile: causal masks
#pragma unroll
      for (int sub = 0; sub < 2; ++sub)
#pragma unroll
        for (int r = 0; r < 4; ++r) {
          const int qt = q0 + sub * 16 + hi * 4 + r;
          const int kv0 = kvb + lc;
          float p0 = (kv0 <= qt) ? exp2f(sc[sub][0][r] * SL) : 0.f;
          float p1 = (kv0 + 16 <= qt) ? exp2f(sc[sub][1][r] * SL) : 0.f;
          lrow[sub][r] += p0 + p1;
          Pw[(sub * 16 + hi * 4 + r) * 40 + lc] = f2bf_t(p0);
          Pw[(sub * 16 + hi * 4 + r) * 40 + 16 + lc] = f2bf_t(p1);
        }
    }
    asm volatile("s_waitcnt lgkmcnt(0)" ::: "memory");
    s16x8 pa0 = *(const s16x8*)&Pw[lc * 40 + hi * 8];
    s16x8 pa1 = *(const s16x8*)&Pw[(16 + lc) * 40 + hi * 8];
#pragma unroll
    for (int nt = 0; nt < 4; ++nt) {
      o[0][nt] = MFMA_BF16(pa0, bv[nt], o[0][nt]);
      o[1][nt] = MFMA_BF16(pa1, bv[nt], o[1][nt]);
    }
  }

#pragma unroll
  for (int sub = 0; sub < 2; ++sub)
#pragma unroll
    for (int r = 0; r < 4; ++r) {
      float l = lrow[sub][r];
      l += __shfl_xor(l, 1);
      l += __shfl_xor(l, 2);
      l += __shfl_xor(l, 4);
      l += __shfl_xor(l, 8);
      lrow[sub][r] = l;
    }

  if (lc == 0) {
#pragma unroll
    for (int sub = 0; sub < 2; ++sub)
#pragma unroll
      for (int r = 0; r < 4; ++r) Pl[w][sub * 16 + hi * 4 + r] = lrow[sub][r];
  }
  float* Pow = &PoS[w][0][0];
#pragma unroll
  for (int sub = 0; sub < 2; ++sub)
#pragma unroll
    for (int nt = 0; nt < 4; ++nt)
#pragma unroll
      for (int r = 0; r < 4; ++r)
        Pow[(sub * 16 + hi * 4 + r) * 66 + nt * 16 + lc] = o[sub][nt][r];
  __syncthreads();

#pragma unroll
  for (int rr = 0; rr < 8; ++rr) {
    const int row = w * 8 + rr;
    float L = Pl[0][row] + Pl[1][row] + Pl[2][row] + Pl[3][row];
    float val = PoS[0][row][lane] + PoS[1][row][lane] + PoS[2][row][lane] + PoS[3][row][lane];
    out[(size_t)(brow + q0 + row) * 64 + lane] = val / L;
  }
}

extern "C" void kernel_launch(void* const* d_in, const int* in_sizes, int n_in,
                              void* d_out, int out_size, void* d_ws, size_t ws_size,
                              hipStream_t stream) {
  (void)in_sizes; (void)n_in; (void)out_size; (void)ws_size;
  const float* x = (const float*)d_in[0];
  const float* Wq = (const float*)d_in[1];
  const float* Wk = (const float*)d_in[2];
  const float* Wv = (const float*)d_in[3];
  float* out = (float*)d_out;

  u16* wsu = (u16*)d_ws;
  u16* Wt = wsu;                      // 128*192*8 = 196608 (k-major layout)
  u16* qb = Wt + 192 * 1024;          // 8*2048*64
  u16* kb = qb + 8 * 2048 * 64;       // 8*2048*64
  u16* vT = kb + 8 * 2048 * 64;       // 8*64*2048
  // total ws use: 6,684,672 bytes

  wt_convert<<<48, 256, 0, stream>>>(Wq, Wk, Wv, Wt);
  qkv_gemm<<<512, 512, 0, stream>>>(x, Wt, qb, kb, vT);
  attn_fwd<<<512, 256, 0, stream>>>(qb, kb, vT, out);
}

// Round 13
// 76.097 us; speedup vs baseline: 1.0275x; 1.0275x over previous
//
#include <hip/hip_runtime.h>
#include <hip/hip_bf16.h>

typedef unsigned short u16;
typedef unsigned int u32;
typedef float f32x4 __attribute__((ext_vector_type(4)));
typedef short s16x8 __attribute__((ext_vector_type(8)));

#define MFMA_BF16(a, b, c) __builtin_amdgcn_mfma_f32_16x16x32_bf16((a), (b), (c), 0, 0, 0)

// Problem constants: B=8, T=2048, D=1024, HS=64; scale = 1/sqrt(2048) (per reference!)

__device__ __forceinline__ u16 f2bf(float f) {
  union { float f; u32 u; } v; v.f = f;
  u32 u = v.u;
  return (u16)((u + 0x7FFFu + ((u >> 16) & 1u)) >> 16);  // RNE f32->bf16
}
__device__ __forceinline__ u16 f2bf_t(float f) {  // truncating f32->bf16 (P tile only)
  union { float f; u32 u; } v; v.f = f;
  return (u16)(v.u >> 16);
}
// native pack: compiler emits v_cvt_pk_bf16_f32
__device__ __forceinline__ s16x8 pack_bf8(float4 a, float4 b) {
  union { __hip_bfloat162 h2[4]; s16x8 s; } u;
  u.h2[0] = __float22bfloat162_rn(make_float2(a.x, a.y));
  u.h2[1] = __float22bfloat162_rn(make_float2(a.z, a.w));
  u.h2[2] = __float22bfloat162_rn(make_float2(b.x, b.y));
  u.h2[3] = __float22bfloat162_rn(make_float2(b.z, b.w));
  return u.s;
}
__device__ __forceinline__ void gload_lds16(const void* g, void* l) {
  __builtin_amdgcn_global_load_lds((const __attribute__((address_space(1))) u32*)g,
                                   (__attribute__((address_space(3))) u32*)l, 16, 0, 0);
}

// ---- Kernel 1: W [1024][64] f32 x3 -> Wt4: the exact LDS image qkv wants.
// Layout: slab (s=matrix, ph=k-half) of 32768 u16; within a slab:
//   u16 idx = col*512 + ((kg ^ (col&15)) << 3) + (k&7),  kg = (k - ph*512)/8
// i.e. [64 col][64 granules of 8 k], granule-XOR-swizzled by col (rule #21:
// the swizzle lives in GLOBAL, staging is a linear 1:1 copy via global_load_lds).
__global__ __launch_bounds__(256) void wt_convert(const float* __restrict__ Wq,
                                                  const float* __restrict__ Wk,
                                                  const float* __restrict__ Wv,
                                                  u16* __restrict__ Wt4) {
  __shared__ u16 Ls[64][70];
  const int bid = blockIdx.x;
  const int m = bid >> 4, d0 = (bid & 15) * 64;
  const float* W = (m == 0) ? Wq : (m == 1) ? Wk : Wv;
  const int t = threadIdx.x;
  {
    const int dr = t >> 2, hc = (t & 3) * 16;
    const float4* src = (const float4*)(W + (size_t)(d0 + dr) * 64 + hc);
    float4 f0 = src[0], f1 = src[1], f2 = src[2], f3 = src[3];
    float fl[16] = {f0.x, f0.y, f0.z, f0.w, f1.x, f1.y, f1.z, f1.w,
                    f2.x, f2.y, f2.z, f2.w, f3.x, f3.y, f3.z, f3.w};
#pragma unroll
    for (int j = 0; j < 8; ++j) {
      u32 pk = (u32)f2bf(fl[2 * j]) | ((u32)f2bf(fl[2 * j + 1]) << 16);
      *(u32*)&Ls[dr][hc + 2 * j] = pk;
    }
  }
  __syncthreads();
  {
    const int h = t >> 2, dcs = (t & 3) * 16;
    u32 po[8];
#pragma unroll
    for (int j = 0; j < 8; ++j)
      po[j] = (u32)Ls[dcs + 2 * j][h] | ((u32)Ls[dcs + 2 * j + 1][h] << 16);
#pragma unroll
    for (int half = 0; half < 2; ++half) {
      const int kg_glob = ((d0 + dcs) >> 3) + half;  // 8-k granule index 0..127
      const int ph = kg_glob >> 6, kgl = kg_glob & 63;
      u16* dst = Wt4 + (size_t)(m * 2 + ph) * 32768 + h * 512 + ((kgl ^ (h & 15)) << 3);
      *(uint4*)dst = make_uint4(po[half * 4], po[half * 4 + 1],
                                po[half * 4 + 2], po[half * 4 + 3]);
    }
  }
}

// ---- Kernel 2: QKV projection, PERSISTENT-W: no W loads in the k-loop.
// C[16384,192] = X[16384,1024] @ W[1024,192], bf16 MFMA.
// Block = (slice s = q/k/v, 128 rows). W-slice half [64 col][512 k] = 64KB LDS,
// loaded ONCE per phase (2 phases, 3 barriers/block total). k-loop per wave:
// 2 x-loads (1-step prefetch, pinned by sched_barrier(0) so the compiler cannot
// sink them -- the r6/r7/r12 failure mode) + 4 LDS B-frag reads + 4 MFMA.
// 512 thr (8 waves; wave = 16 rows x 4 n-tiles, acc 16 VGPR), grid 3*128=384,
// 2 blocks/CU (64KB) = 16 waves/CU. B-reads 2-way banks via col-XOR swizzle.
__global__ __launch_bounds__(512) void qkv_gemm(const float* __restrict__ x,
                                                const u16* __restrict__ Wt4,
                                                u16* __restrict__ qo,
                                                u16* __restrict__ ko,
                                                u16* __restrict__ vTo) {
  __shared__ u16 Wl[32768];  // [64 col][512 k] bf16, granule-swizzled (64 KB)
  const int tid = threadIdx.x, lane = tid & 63, w = tid >> 6;
  const int lc = lane & 15, hi = lane >> 4;
  const int bid = blockIdx.x;
  const int s = bid % 3;                 // slice: 0=q, 1=k, 2=v
  const int m0 = (bid / 3) * 128;        // row block
  // wave w owns rows m0 + w*16 .. +15

  f32x4 acc[4];
#pragma unroll
  for (int i = 0; i < 4; ++i) acc[i] = (f32x4){0.f, 0.f, 0.f, 0.f};

  const float* xp = x + (size_t)(m0 + w * 16 + lc) * 1024 + hi * 8;

  // B-frag LDS offsets (u16 units), fixed per lane up to kg
  int bcol[4];
#pragma unroll
  for (int nt = 0; nt < 4; ++nt) bcol[nt] = (nt * 16 + lc) * 512;
  const int bxor = lc & 15;

  for (int ph = 0; ph < 2; ++ph) {
    // stage 64KB W-slab: 4096 x 16B chunks, 512 threads -> 8 rounds (linear copy)
    const u16* slab = Wt4 + (size_t)(s * 2 + ph) * 32768;
#pragma unroll
    for (int i = 0; i < 8; ++i) {
      const int chunk = i * 512 + tid;
      gload_lds16(slab + chunk * 8, &Wl[chunk * 8]);
    }
    __syncthreads();  // drains staging; once per 16 k-steps, not per step

    const float* xq = xp + ph * 512;
    float4 xa = *(const float4*)xq;
    float4 xb = *(const float4*)(xq + 4);
    for (int kk = 0; kk < 16; ++kk) {
      float4 na, nb;
      if (kk < 15) {  // issue next step's x loads
        na = *(const float4*)(xq + kk * 32 + 32);
        nb = *(const float4*)(xq + kk * 32 + 36);
      }
      __builtin_amdgcn_sched_barrier(0);  // pin: loads stay issued above the MFMAs
      s16x8 a = pack_bf8(xa, xb);
      const int kg = kk * 4 + hi;
#pragma unroll
      for (int nt = 0; nt < 4; ++nt) {
        s16x8 bfr = *(const s16x8*)&Wl[bcol[nt] + ((kg ^ bxor) << 3)];
        acc[nt] = MFMA_BF16(a, bfr, acc[nt]);
      }
      if (kk < 15) { xa = na; xb = nb; }
    }
    if (ph == 0) __syncthreads();  // all waves done reading before restage
  }

  // epilogue: C layout col=lane&15, row=(lane>>4)*4+r; slice-uniform dest
#pragma unroll
  for (int nt = 0; nt < 4; ++nt) {
#pragma unroll
    for (int r = 0; r < 4; ++r) {
      const int gr = m0 + w * 16 + hi * 4 + r;
      const int col = nt * 16 + lc;
      const u16 val = f2bf(acc[nt][r]);
      if (s == 0) {
        qo[gr * 64 + col] = val;
      } else if (s == 1) {
        ko[gr * 64 + col] = val;
      } else {
        const int b = gr >> 11, t2 = gr & 2047;
        vTo[((b << 6) + col) * 2048 + t2] = val;
      }
    }
  }
}

// ---- Kernel 3: causal flash attention, no-max softmax. 256 threads = 4 waves.
// (unchanged from round 5: proven)
__global__ __launch_bounds__(256, 2) void attn_fwd(const u16* __restrict__ qb,
                                                   const u16* __restrict__ kb,
                                                   const u16* __restrict__ vT,
                                                   float* __restrict__ out) {
  __shared__ float PoS[4][32][66];  // per-wave merge buffer; P tile [32][40]u16 unioned in
  __shared__ float Pl[4][32];       // per-wave denominator partials
  const int tid = threadIdx.x, lane = tid & 63, w = tid >> 6;
  const int lc = lane & 15, hi = lane >> 4;
  const int bid = blockIdx.x;
  const int b = bid & 7, v = 63 - (bid >> 3);  // batch, q-tile id (heavy-first)
  const int q0 = v * 32;                       // q-tile base row within batch
  const int brow = b * 2048;
  u16* Pw = (u16*)&PoS[w][0][0];  // [32][40] u16 view, per-wave

  s16x8 aq[2][2];
#pragma unroll
  for (int sub = 0; sub < 2; ++sub) {
    const u16* qrow = qb + (size_t)(brow + q0 + sub * 16 + lc) * 64;
    aq[sub][0] = *(const s16x8*)(qrow + hi * 8);
    aq[sub][1] = *(const s16x8*)(qrow + 32 + hi * 8);
  }

  f32x4 o[2][4];
  float lrow[2][4];
#pragma unroll
  for (int sub = 0; sub < 2; ++sub)
#pragma unroll
    for (int i = 0; i < 4; ++i) {
      o[sub][i] = (f32x4){0.f, 0.f, 0.f, 0.f};
      lrow[sub][i] = 0.f;
    }

  const float SL = 0.031879357f;  // (1/sqrt(2048)) * log2(e)
  const int nk = v + 1;           // causal kv-tiles of 32 for this q-tile
  const int c = (nk + 3) >> 2;    // chunk per split-wave (4-way)
  const int s = w;
  const int it0 = s * c;
  const int it1 = min(it0 + c, nk);

  const u16* kbase = kb + (size_t)brow * 64;

  for (int it = it0; it < it1; ++it) {
    const int kvb = it * 32;
    const u16* krow0 = kbase + (size_t)(kvb + lc) * 64;
    const u16* krow1 = kbase + (size_t)(kvb + 16 + lc) * 64;
    s16x8 k00 = *(const s16x8*)(krow0 + hi * 8);
    s16x8 k01 = *(const s16x8*)(krow0 + 32 + hi * 8);
    s16x8 k10 = *(const s16x8*)(krow1 + hi * 8);
    s16x8 k11 = *(const s16x8*)(krow1 + 32 + hi * 8);
    s16x8 bv[4];
#pragma unroll
    for (int nt = 0; nt < 4; ++nt)
      bv[nt] = *(const s16x8*)&vT[(size_t)(b * 64 + nt * 16 + lc) * 2048 + kvb + hi * 8];

    f32x4 sc[2][2];
#pragma unroll
    for (int sub = 0; sub < 2; ++sub) {
      sc[sub][0] = (f32x4){0.f, 0.f, 0.f, 0.f};
      sc[sub][1] = (f32x4){0.f, 0.f, 0.f, 0.f};
      sc[sub][0] = MFMA_BF16(aq[sub][0], k00, sc[sub][0]);
      sc[sub][0] = MFMA_BF16(aq[sub][1], k01, sc[sub][0]);
      sc[sub][1] = MFMA_BF16(aq[sub][0], k10, sc[sub][1]);
      sc[sub][1] = MFMA_BF16(aq[sub][1], k11, sc[sub][1]);
    }

    if (kvb + 31 <= q0) {  // tile fully below diagonal: no masks
#pragma unroll
      for (int sub = 0; sub < 2; ++sub)
#pragma unroll
        for (int r = 0; r < 4; ++r) {
          float p0 = exp2f(sc[sub][0][r] * SL);
          float p1 = exp2f(sc[sub][1][r] * SL);
          lrow[sub][r] += p0 + p1;
          Pw[(sub * 16 + hi * 4 + r) * 40 + lc] = f2bf_t(p0);
          Pw[(sub * 16 + hi * 4 + r) * 40 + 16 + lc] = f2bf_t(p1);
        }
    } else {  // diagonal tile: causal masks
#pragma unroll
      for (int sub = 0; sub < 2; ++sub)
#pragma unroll
        for (int r = 0; r < 4; ++r) {
          const int qt = q0 + sub * 16 + hi * 4 + r;
          const int kv0 = kvb + lc;
          float p0 = (kv0 <= qt) ? exp2f(sc[sub][0][r] * SL) : 0.f;
          float p1 = (kv0 + 16 <= qt) ? exp2f(sc[sub][1][r] * SL) : 0.f;
          lrow[sub][r] += p0 + p1;
          Pw[(sub * 16 + hi * 4 + r) * 40 + lc] = f2bf_t(p0);
          Pw[(sub * 16 + hi * 4 + r) * 40 + 16 + lc] = f2bf_t(p1);
        }
    }
    asm volatile("s_waitcnt lgkmcnt(0)" ::: "memory");
    s16x8 pa0 = *(const s16x8*)&Pw[lc * 40 + hi * 8];
    s16x8 pa1 = *(const s16x8*)&Pw[(16 + lc) * 40 + hi * 8];
#pragma unroll
    for (int nt = 0; nt < 4; ++nt) {
      o[0][nt] = MFMA_BF16(pa0, bv[nt], o[0][nt]);
      o[1][nt] = MFMA_BF16(pa1, bv[nt], o[1][nt]);
    }
  }

#pragma unroll
  for (int sub = 0; sub < 2; ++sub)
#pragma unroll
    for (int r = 0; r < 4; ++r) {
      float l = lrow[sub][r];
      l += __shfl_xor(l, 1);
      l += __shfl_xor(l, 2);
      l += __shfl_xor(l, 4);
      l += __shfl_xor(l, 8);
      lrow[sub][r] = l;
    }

  if (lc == 0) {
#pragma unroll
    for (int sub = 0; sub < 2; ++sub)
#pragma unroll
      for (int r = 0; r < 4; ++r) Pl[w][sub * 16 + hi * 4 + r] = lrow[sub][r];
  }
  float* Pow = &PoS[w][0][0];
#pragma unroll
  for (int sub = 0; sub < 2; ++sub)
#pragma unroll
    for (int nt = 0; nt < 4; ++nt)
#pragma unroll
      for (int r = 0; r < 4; ++r)
        Pow[(sub * 16 + hi * 4 + r) * 66 + nt * 16 + lc] = o[sub][nt][r];
  __syncthreads();

#pragma unroll
  for (int rr = 0; rr < 8; ++rr) {
    const int row = w * 8 + rr;
    float L = Pl[0][row] + Pl[1][row] + Pl[2][row] + Pl[3][row];
    float val = PoS[0][row][lane] + PoS[1][row][lane] + PoS[2][row][lane] + PoS[3][row][lane];
    out[(size_t)(brow + q0 + row) * 64 + lane] = val / L;
  }
}

extern "C" void kernel_launch(void* const* d_in, const int* in_sizes, int n_in,
                              void* d_out, int out_size, void* d_ws, size_t ws_size,
                              hipStream_t stream) {
  (void)in_sizes; (void)n_in; (void)out_size; (void)ws_size;
  const float* x = (const float*)d_in[0];
  const float* Wq = (const float*)d_in[1];
  const float* Wk = (const float*)d_in[2];
  const float* Wv = (const float*)d_in[3];
  float* out = (float*)d_out;

  u16* wsu = (u16*)d_ws;
  u16* Wt = wsu;                      // 3*2*32768 = 196608 u16 (LDS-image layout)
  u16* qb = Wt + 192 * 1024;          // 8*2048*64
  u16* kb = qb + 8 * 2048 * 64;       // 8*2048*64
  u16* vT = kb + 8 * 2048 * 64;       // 8*64*2048
  // total ws use: 6,684,672 bytes

  wt_convert<<<48, 256, 0, stream>>>(Wq, Wk, Wv, Wt);
  qkv_gemm<<<384, 512, 0, stream>>>(x, Wt, qb, kb, vT);
  attn_fwd<<<512, 256, 0, stream>>>(qb, kb, vT, out);
}

// Round 14
// 57.472 us; speedup vs baseline: 1.3605x; 1.3241x over previous
//
#include <hip/hip_runtime.h>
#include <hip/hip_bf16.h>

typedef unsigned short u16;
typedef unsigned int u32;
typedef float f32x4 __attribute__((ext_vector_type(4)));
typedef short s16x8 __attribute__((ext_vector_type(8)));

#define MFMA_BF16(a, b, c) __builtin_amdgcn_mfma_f32_16x16x32_bf16((a), (b), (c), 0, 0, 0)

// Problem constants: B=8, T=2048, D=1024, HS=64; scale = 1/sqrt(2048) (per reference!)

__device__ __forceinline__ u16 f2bf(float f) {
  union { float f; u32 u; } v; v.f = f;
  u32 u = v.u;
  return (u16)((u + 0x7FFFu + ((u >> 16) & 1u)) >> 16);  // RNE f32->bf16
}
__device__ __forceinline__ u16 f2bf_t(float f) {  // truncating f32->bf16 (P tile only)
  union { float f; u32 u; } v; v.f = f;
  return (u16)(v.u >> 16);
}
// native pack: compiler emits v_cvt_pk_bf16_f32
__device__ __forceinline__ s16x8 pack_bf8(float4 a, float4 b) {
  union { __hip_bfloat162 h2[4]; s16x8 s; } u;
  u.h2[0] = __float22bfloat162_rn(make_float2(a.x, a.y));
  u.h2[1] = __float22bfloat162_rn(make_float2(a.z, a.w));
  u.h2[2] = __float22bfloat162_rn(make_float2(b.x, b.y));
  u.h2[3] = __float22bfloat162_rn(make_float2(b.z, b.w));
  return u.s;
}
__device__ __forceinline__ void gload_lds16(const void* g, void* l) {
  __builtin_amdgcn_global_load_lds((const __attribute__((address_space(1))) u32*)g,
                                   (__attribute__((address_space(3))) u32*)l, 16, 0, 0);
}

// ---- Kernel 1: W [1024][64] f32 x3 -> Wt3 bf16 [32 kstep][192 row][32 k] LINEAR
// (rows: q 0-63, k 64-127, v 128-191). Each k-step's W = one contiguous 12KB chunk.
// (qkv's staging computes the swizzled SOURCE address itself; global layout stays linear.)
__global__ __launch_bounds__(256) void wt_convert(const float* __restrict__ Wq,
                                                  const float* __restrict__ Wk,
                                                  const float* __restrict__ Wv,
                                                  u16* __restrict__ Wt3) {
  __shared__ u16 Ls[64][70];
  const int bid = blockIdx.x;
  const int m = bid >> 4, d0 = (bid & 15) * 64;
  const float* W = (m == 0) ? Wq : (m == 1) ? Wk : Wv;
  const int t = threadIdx.x;
  {
    const int dr = t >> 2, hc = (t & 3) * 16;
    const float4* src = (const float4*)(W + (size_t)(d0 + dr) * 64 + hc);
    float4 f0 = src[0], f1 = src[1], f2 = src[2], f3 = src[3];
    float fl[16] = {f0.x, f0.y, f0.z, f0.w, f1.x, f1.y, f1.z, f1.w,
                    f2.x, f2.y, f2.z, f2.w, f3.x, f3.y, f3.z, f3.w};
#pragma unroll
    for (int j = 0; j < 8; ++j) {
      u32 pk = (u32)f2bf(fl[2 * j]) | ((u32)f2bf(fl[2 * j + 1]) << 16);
      *(u32*)&Ls[dr][hc + 2 * j] = pk;
    }
  }
  __syncthreads();
  {
    const int h = t >> 2, dcs = (t & 3) * 16;
    const int grow = m * 64 + h;
    const int dd = d0 + dcs;
    u32 po[8];
#pragma unroll
    for (int j = 0; j < 8; ++j)
      po[j] = (u32)Ls[dcs + 2 * j][h] | ((u32)Ls[dcs + 2 * j + 1][h] << 16);
    u16* dst = Wt3 + ((size_t)(dd >> 5) * 192 + grow) * 32 + (dd & 31);
    *(uint4*)&dst[0] = make_uint4(po[0], po[1], po[2], po[3]);
    *(uint4*)&dst[8] = make_uint4(po[4], po[5], po[6], po[7]);
  }
}

// ---- Kernel 2: QKV projection. C[16384,192] = X[16384,1024] @ W[1024,192], bf16 MFMA.
// THE M97 REGIME: simple 2-phase gload_lds loop at 4 BLOCKS/CU (32 waves/CU) so the
// barrier's vmcnt(0) drain of one block hides under the other three blocks' compute
// (m114 mechanism; every prior attempt ran 1-2 blocks/CU -- that was the bug class).
// BM=32, BN=192, BK=32, 512 thr (8 waves), grid 512, LDS 32KB/block.
// Wave (msub=w&1, ntg=w>>1): 16 rows x 3 n-tiles, 3 MFMA/step, acc[3].
// Swizzles both-sides (rule #21; permutation carried in the staging SOURCE addr,
// LDS dest linear): X granule16 ^= row&7; W granule16 ^= (row>>1)&3 -> 2-way banks.
__global__ __launch_bounds__(512) void qkv_gemm(const float* __restrict__ x,
                                                const u16* __restrict__ Wt3,
                                                u16* __restrict__ qo,
                                                u16* __restrict__ ko,
                                                u16* __restrict__ vTo) {
  __shared__ float Xf[2][1024];  // [32 row][32 f32] 4KB/buf, swizzled
  __shared__ u16 Wl[2][6144];    // [192 row][32 bf16] 12KB/buf, swizzled
  const int tid = threadIdx.x, lane = tid & 63, w = tid >> 6;
  const int lc = lane & 15, hi = lane >> 4;
  const int m0 = blockIdx.x * 32;
  const int msub = w & 1, ntg = w >> 1;

  f32x4 acc[3];
#pragma unroll
  for (int i = 0; i < 3; ++i) acc[i] = (f32x4){0.f, 0.f, 0.f, 0.f};

  // X staging (tid<256): chunk c=tid -> row=c>>3, dest granule gd=c&7;
  // source granule gs = gd ^ (row&7)  (inverse of the read swizzle).
  const int xrow = tid >> 3;
  const int xgs = (tid & 7) ^ ((tid >> 3) & 7);
  const float* xsrc = x + (size_t)(m0 + xrow) * 1024 + xgs * 4;
  // W staging: chunks c0=tid (all), c1=tid+512 (tid<256): row=c>>2, gd=c&3,
  // source granule gs = gd ^ ((row>>1)&3).
  const int w0r = tid >> 2, w0g = (tid & 3) ^ ((tid >> 3) & 3);
  const int c1 = tid + 512;
  const int w1r = c1 >> 2, w1g = (c1 & 3) ^ ((c1 >> 3) & 3);

  auto stage = [&](int t, int bf) {
    if (tid < 256) gload_lds16(xsrc + (size_t)t * 32, &Xf[bf][tid * 4]);
    gload_lds16(Wt3 + (size_t)t * 6144 + w0r * 32 + w0g * 8, &Wl[bf][tid * 8]);
    if (tid < 256)
      gload_lds16(Wt3 + (size_t)t * 6144 + w1r * 32 + w1g * 8, &Wl[bf][c1 * 8]);
  };

  // swizzled read offsets
  const int rA = msub * 16 + lc;
  const int aof0 = rA * 32 + (((hi * 2) ^ (rA & 7)) << 2);
  const int aof1 = rA * 32 + (((hi * 2 + 1) ^ (rA & 7)) << 2);
  int bof[3];
#pragma unroll
  for (int j = 0; j < 3; ++j) {
    const int rB = (ntg * 3 + j) * 16 + lc;
    bof[j] = rB * 32 + ((hi ^ ((rB >> 1) & 3)) << 3);
  }

  stage(0, 0);
  __syncthreads();
  int buf = 0;

  for (int t = 0; t < 32; ++t) {
    if (t < 31) stage(t + 1, buf ^ 1);
    float4 alo = *(const float4*)&Xf[buf][aof0];
    float4 ahi = *(const float4*)&Xf[buf][aof1];
    s16x8 a = pack_bf8(alo, ahi);
#pragma unroll
    for (int j = 0; j < 3; ++j) {
      s16x8 bfr = *(const s16x8*)&Wl[buf][bof[j]];
      acc[j] = MFMA_BF16(a, bfr, acc[j]);
    }
    if (t < 31) {
      __syncthreads();
      buf ^= 1;
    }
  }

  // epilogue: C layout col=lane&15, row=(lane>>4)*4+r
#pragma unroll
  for (int j = 0; j < 3; ++j) {
    const int nt = ntg * 3 + j;
#pragma unroll
    for (int r = 0; r < 4; ++r) {
      const int gr = m0 + msub * 16 + hi * 4 + r;
      const u16 val = f2bf(acc[j][r]);
      const int n = nt * 16 + lc;
      if (nt < 4) {
        qo[gr * 64 + n] = val;
      } else if (nt < 8) {
        ko[gr * 64 + (n - 64)] = val;
      } else {
        int b = gr >> 11, t2 = gr & 2047;
        vTo[((b << 6) + (n - 128)) * 2048 + t2] = val;
      }
    }
  }
}

// ---- Kernel 3: causal flash attention, no-max softmax. 256 threads = 4 waves.
// (unchanged from round 5: proven ~15us)
__global__ __launch_bounds__(256, 2) void attn_fwd(const u16* __restrict__ qb,
                                                   const u16* __restrict__ kb,
                                                   const u16* __restrict__ vT,
                                                   float* __restrict__ out) {
  __shared__ float PoS[4][32][66];  // per-wave merge buffer; P tile [32][40]u16 unioned in
  __shared__ float Pl[4][32];       // per-wave denominator partials
  const int tid = threadIdx.x, lane = tid & 63, w = tid >> 6;
  const int lc = lane & 15, hi = lane >> 4;
  const int bid = blockIdx.x;
  const int b = bid & 7, v = 63 - (bid >> 3);  // batch, q-tile id (heavy-first)
  const int q0 = v * 32;                       // q-tile base row within batch
  const int brow = b * 2048;
  u16* Pw = (u16*)&PoS[w][0][0];  // [32][40] u16 view, per-wave

  s16x8 aq[2][2];
#pragma unroll
  for (int sub = 0; sub < 2; ++sub) {
    const u16* qrow = qb + (size_t)(brow + q0 + sub * 16 + lc) * 64;
    aq[sub][0] = *(const s16x8*)(qrow + hi * 8);
    aq[sub][1] = *(const s16x8*)(qrow + 32 + hi * 8);
  }

  f32x4 o[2][4];
  float lrow[2][4];
#pragma unroll
  for (int sub = 0; sub < 2; ++sub)
#pragma unroll
    for (int i = 0; i < 4; ++i) {
      o[sub][i] = (f32x4){0.f, 0.f, 0.f, 0.f};
      lrow[sub][i] = 0.f;
    }

  const float SL = 0.031879357f;  // (1/sqrt(2048)) * log2(e)
  const int nk = v + 1;           // causal kv-tiles of 32 for this q-tile
  const int c = (nk + 3) >> 2;    // chunk per split-wave (4-way)
  const int s = w;
  const int it0 = s * c;
  const int it1 = min(it0 + c, nk);

  const u16* kbase = kb + (size_t)brow * 64;

  for (int it = it0; it < it1; ++it) {
    const int kvb = it * 32;
    const u16* krow0 = kbase + (size_t)(kvb + lc) * 64;
    const u16* krow1 = kbase + (size_t)(kvb + 16 + lc) * 64;
    s16x8 k00 = *(const s16x8*)(krow0 + hi * 8);
    s16x8 k01 = *(const s16x8*)(krow0 + 32 + hi * 8);
    s16x8 k10 = *(const s16x8*)(krow1 + hi * 8);
    s16x8 k11 = *(const s16x8*)(krow1 + 32 + hi * 8);
    s16x8 bv[4];
#pragma unroll
    for (int nt = 0; nt < 4; ++nt)
      bv[nt] = *(const s16x8*)&vT[(size_t)(b * 64 + nt * 16 + lc) * 2048 + kvb + hi * 8];

    f32x4 sc[2][2];
#pragma unroll
    for (int sub = 0; sub < 2; ++sub) {
      sc[sub][0] = (f32x4){0.f, 0.f, 0.f, 0.f};
      sc[sub][1] = (f32x4){0.f, 0.f, 0.f, 0.f};
      sc[sub][0] = MFMA_BF16(aq[sub][0], k00, sc[sub][0]);
      sc[sub][0] = MFMA_BF16(aq[sub][1], k01, sc[sub][0]);
      sc[sub][1] = MFMA_BF16(aq[sub][0], k10, sc[sub][1]);
      sc[sub][1] = MFMA_BF16(aq[sub][1], k11, sc[sub][1]);
    }

    if (kvb + 31 <= q0) {  // tile fully below diagonal: no masks
#pragma unroll
      for (int sub = 0; sub < 2; ++sub)
#pragma unroll
        for (int r = 0; r < 4; ++r) {
          float p0 = exp2f(sc[sub][0][r] * SL);
          float p1 = exp2f(sc[sub][1][r] * SL);
          lrow[sub][r] += p0 + p1;
          Pw[(sub * 16 + hi * 4 + r) * 40 + lc] = f2bf_t(p0);
          Pw[(sub * 16 + hi * 4 + r) * 40 + 16 + lc] = f2bf_t(p1);
        }
    } else {  // diagonal tile: causal masks
#pragma unroll
      for (int sub = 0; sub < 2; ++sub)
#pragma unroll
        for (int r = 0; r < 4; ++r) {
          const int qt = q0 + sub * 16 + hi * 4 + r;
          const int kv0 = kvb + lc;
          float p0 = (kv0 <= qt) ? exp2f(sc[sub][0][r] * SL) : 0.f;
          float p1 = (kv0 + 16 <= qt) ? exp2f(sc[sub][1][r] * SL) : 0.f;
          lrow[sub][r] += p0 + p1;
          Pw[(sub * 16 + hi * 4 + r) * 40 + lc] = f2bf_t(p0);
          Pw[(sub * 16 + hi * 4 + r) * 40 + 16 + lc] = f2bf_t(p1);
        }
    }
    asm volatile("s_waitcnt lgkmcnt(0)" ::: "memory");
    s16x8 pa0 = *(const s16x8*)&Pw[lc * 40 + hi * 8];
    s16x8 pa1 = *(const s16x8*)&Pw[(16 + lc) * 40 + hi * 8];
#pragma unroll
    for (int nt = 0; nt < 4; ++nt) {
      o[0][nt] = MFMA_BF16(pa0, bv[nt], o[0][nt]);
      o[1][nt] = MFMA_BF16(pa1, bv[nt], o[1][nt]);
    }
  }

#pragma unroll
  for (int sub = 0; sub < 2; ++sub)
#pragma unroll
    for (int r = 0; r < 4; ++r) {
      float l = lrow[sub][r];
      l += __shfl_xor(l, 1);
      l += __shfl_xor(l, 2);
      l += __shfl_xor(l, 4);
      l += __shfl_xor(l, 8);
      lrow[sub][r] = l;
    }

  if (lc == 0) {
#pragma unroll
    for (int sub = 0; sub < 2; ++sub)
#pragma unroll
      for (int r = 0; r < 4; ++r) Pl[w][sub * 16 + hi * 4 + r] = lrow[sub][r];
  }
  float* Pow = &PoS[w][0][0];
#pragma unroll
  for (int sub = 0; sub < 2; ++sub)
#pragma unroll
    for (int nt = 0; nt < 4; ++nt)
#pragma unroll
      for (int r = 0; r < 4; ++r)
        Pow[(sub * 16 + hi * 4 + r) * 66 + nt * 16 + lc] = o[sub][nt][r];
  __syncthreads();

#pragma unroll
  for (int rr = 0; rr < 8; ++rr) {
    const int row = w * 8 + rr;
    float L = Pl[0][row] + Pl[1][row] + Pl[2][row] + Pl[3][row];
    float val = PoS[0][row][lane] + PoS[1][row][lane] + PoS[2][row][lane] + PoS[3][row][lane];
    out[(size_t)(brow + q0 + row) * 64 + lane] = val / L;
  }
}

extern "C" void kernel_launch(void* const* d_in, const int* in_sizes, int n_in,
                              void* d_out, int out_size, void* d_ws, size_t ws_size,
                              hipStream_t stream) {
  (void)in_sizes; (void)n_in; (void)out_size; (void)ws_size;
  const float* x = (const float*)d_in[0];
  const float* Wq = (const float*)d_in[1];
  const float* Wk = (const float*)d_in[2];
  const float* Wv = (const float*)d_in[3];
  float* out = (float*)d_out;

  u16* wsu = (u16*)d_ws;
  u16* Wt = wsu;                      // 32*192*32 = 196608 (k-step-major layout)
  u16* qb = Wt + 192 * 1024;          // 8*2048*64
  u16* kb = qb + 8 * 2048 * 64;       // 8*2048*64
  u16* vT = kb + 8 * 2048 * 64;       // 8*64*2048
  // total ws use: 6,684,672 bytes

  wt_convert<<<48, 256, 0, stream>>>(Wq, Wk, Wv, Wt);
  qkv_gemm<<<512, 512, 0, stream>>>(x, Wt, qb, kb, vT);
  attn_fwd<<<512, 256, 0, stream>>>(qb, kb, vT, out);
}